// Round 1
// 1326.459 us; speedup vs baseline: 1.4386x; 1.4386x over previous
//
#include <hip/hip_runtime.h>
#include <hip/hip_bf16.h>

#define NN 100000
#define NE 1600000
#define XD 4
#define ED 39
#define K1 43    // XD+ED
#define H1 64
#define H2 128
#define H3 256
#define NBN 16   // nodes per block in edge_agg kernel
#define NBK 16   // nodes per block in node kernel

// MFMA fragment types (per guide: ext_vector short8 for bf16 A/B, float4 for C/D)
typedef short bfrag8 __attribute__((ext_vector_type(8)));
typedef float facc4  __attribute__((ext_vector_type(4)));
typedef unsigned short u16x4 __attribute__((ext_vector_type(4)));

// fp32 -> bf16 (RNE) and back, bit-level (inputs are finite, no NaN handling needed)
static __device__ __forceinline__ unsigned short f2bf(float f) {
    union { float f; unsigned int u; } v; v.f = f;
    unsigned int r = v.u + 0x7fffu + ((v.u >> 16) & 1u);
    return (unsigned short)(r >> 16);
}
static __device__ __forceinline__ float bf2f(unsigned short h) {
    union { unsigned int u; float f; } v; v.u = ((unsigned int)h) << 16;
    return v.f;
}

// ---------------- pass 1: indegree histogram
__global__ __launch_bounds__(256) void hist_kernel(const int* __restrict__ eidx,
                                                   int* __restrict__ cnt) {
    int e = blockIdx.x * 256 + threadIdx.x;
    if (e < NE) atomicAdd(&cnt[eidx[e]], 1);
}

// ---------------- pass 2: single-block scan -> row_ptr (incl-shifted) + cursor (excl)
__global__ __launch_bounds__(1024) void scan_kernel(const int* __restrict__ cnt,
                                                    int* __restrict__ row_ptr,
                                                    int* __restrict__ cursor) {
    __shared__ int wsum[16];
    const int t = threadIdx.x, lane = t & 63, w = t >> 6;
    int carry = 0;
    if (t == 0) row_ptr[0] = 0;
    for (int base = 0; base < NN; base += 1024) {
        int i = base + t;
        int v = (i < NN) ? cnt[i] : 0;
        int s = v;
        #pragma unroll
        for (int d = 1; d < 64; d <<= 1) {
            int u = __shfl_up(s, d, 64);
            if (lane >= d) s += u;
        }
        if (lane == 63) wsum[w] = s;
        __syncthreads();
        if (w == 0 && lane < 16) {
            int e = wsum[lane];
            #pragma unroll
            for (int d = 1; d < 16; d <<= 1) {
                int u = __shfl_up(e, d, 64);
                if (lane >= d) e += u;
            }
            wsum[lane] = e;
        }
        __syncthreads();
        int woff = (w == 0) ? 0 : wsum[w - 1];
        int tot  = wsum[15];
        if (i < NN) {
            int incl = carry + woff + s;
            row_ptr[i + 1] = incl;
            cursor[i]      = incl - v;
        }
        carry += tot;
        __syncthreads();
    }
}

// ---------------- pass 3: scatter edge ids into dst-sorted order
__global__ __launch_bounds__(256) void build_kernel(const int* __restrict__ eidx,
                                                    int* __restrict__ cursor,
                                                    int* __restrict__ perm) {
    int e = blockIdx.x * 256 + threadIdx.x;
    if (e < NE) {
        int r = eidx[e];
        int pos = atomicAdd(&cursor[r], 1);
        perm[pos] = e;
    }
}

// ---------------- pass 4: edge MLP via bf16x3 MFMA + deterministic aggregation
//
// Per 64-edge tile:
//   A  = [64 edges][64 k]  (k = 4 x-feats + 39 edge-feats, zero-padded to 64),
//        split into bf16 hi/lo planes in LDS, stride 72 bf16 (144B -> uniform banks
//        for the b128 fragment reads; 128B stride would be a 16-way conflict).
//   L1 = A @ W1 (+b1, relu) -> h1 [64][64] hi/lo planes in LDS.
//   L2 = h1 @ W2 (+b2, relu) -> fragment accumulators -> sRed [128 cols][64 edges]
//        (overlays A/h1 region) -> scalar segment reduce into accs[16][128].
// Weights are register-resident B-fragments (hi/lo), built once per block.
// bf16x3: D += Ahi*Whi + Alo*Whi + Ahi*Wlo  (residual ~2^-17 relative).
//
// Fragment-layout contract used (only assumptions):
//   A/B: M/N index = lane&15; k selected by (lane>>4, reg). A and B frags are
//        built with the SAME k address function, so the exact hw k-permutation
//        cancels (sum over k is order-invariant).
//   D:   row = (lane>>4)*4 + j, col = lane&15   (m89-verified).
__global__ __launch_bounds__(256, 3) void edge_agg_kernel(
    const float* __restrict__ x, const int* __restrict__ eidx,
    const float* __restrict__ ea,
    const float* __restrict__ W1, const float* __restrict__ b1,
    const float* __restrict__ W2, const float* __restrict__ b2,
    const int* __restrict__ row_ptr, const int* __restrict__ perm,
    float* __restrict__ mean)
{
    // union region: Ahi|Alo|H1hi|H1lo, each [64][72] bf16 = 9216B -> 36864B total.
    // sRed overlays it: [128][65] f32 = 33280B <= 36864B.
    __shared__ __align__(16) unsigned short uMem[4 * 64 * 72];
    __shared__ float accs[16 * 129];
    __shared__ int sPerm[64], sCol[64], sRP[NBN + 1];

    unsigned short* Ahi  = uMem;
    unsigned short* Alo  = uMem + 64 * 72;
    unsigned short* H1hi = uMem + 2 * 64 * 72;
    unsigned short* H1lo = uMem + 3 * 64 * 72;
    float* sRed = (float*)uMem;

    const int t    = threadIdx.x;
    const int lane = t & 63;
    const int wid  = t >> 6;       // wave id 0..3
    const int cl   = lane & 15;    // M/N fragment index
    const int lg   = lane >> 4;    // k-group 0..3
    const int n0   = blockIdx.x * NBN;

    if (t <= NBN) sRP[t] = row_ptr[n0 + t];
    for (int i = t; i < NBN * H2; i += 256) accs[(i >> 7) * 129 + (i & 127)] = 0.f;

    // ---- build register-resident weight fragments (once per block)
    // wave wid owns L1 cols [wid*16, wid*16+16) and L2 cols [wid*32, wid*32+32)
    bfrag8 w1h[2], w1l[2];          // [ks]
    bfrag8 w2h[2][2], w2l[2][2];    // [nt][ks]
    const float bias1 = b1[wid * 16 + cl];
    const float bias2[2] = { b2[wid * 32 + cl], b2[wid * 32 + 16 + cl] };
    #pragma unroll
    for (int ks = 0; ks < 2; ks++) {
        #pragma unroll
        for (int j = 0; j < 8; j++) {
            int k = ks * 32 + lg * 8 + j;
            float w = (k < K1) ? W1[k * H1 + wid * 16 + cl] : 0.f;
            unsigned short h = f2bf(w);
            w1h[ks][j] = (short)h;
            w1l[ks][j] = (short)f2bf(w - bf2f(h));
        }
    }
    #pragma unroll
    for (int nt = 0; nt < 2; nt++)
        #pragma unroll
        for (int ks = 0; ks < 2; ks++)
            #pragma unroll
            for (int j = 0; j < 8; j++) {
                int k = ks * 32 + lg * 8 + j;
                float w = W2[k * H2 + wid * 32 + nt * 16 + cl];
                unsigned short h = f2bf(w);
                w2h[nt][ks][j] = (short)h;
                w2l[nt][ks][j] = (short)f2bf(w - bf2f(h));
            }
    __syncthreads();

    const int base = sRP[0], cntE = sRP[NBN] - base;

    for (int tb = 0; tb < cntE; tb += 64) {
        const int nv = min(64, cntE - tb);
        if (t < 64) {
            int e = (t < nv) ? perm[base + tb + t] : -1;
            sPerm[t] = e;
            sCol[t]  = (e >= 0) ? eidx[NE + e] : 0;   // second row = source node
        }
        __syncthreads();   // also protects sRed (prev tile) before A overwrite

        // ---- stage A: 16 bf16 (hi+lo) per thread, full [64][64] incl. zero pad
        #pragma unroll
        for (int r = 0; r < 4; r++) {
            int e  = (t >> 4) + r * 16;
            int k0 = (t & 15) * 4;
            int ee = sPerm[e];
            float v[4];
            if (ee >= 0) {
                if (k0 == 0) {
                    float4 xv = *(const float4*)&x[(size_t)sCol[e] * XD];
                    v[0] = xv.x; v[1] = xv.y; v[2] = xv.z; v[3] = xv.w;
                } else {
                    const float* er = ea + (size_t)ee * ED;
                    #pragma unroll
                    for (int q = 0; q < 4; q++) {
                        int k = k0 + q;
                        v[q] = (k < K1) ? er[k - XD] : 0.f;
                    }
                }
            } else {
                v[0] = v[1] = v[2] = v[3] = 0.f;
            }
            u16x4 hv, lv;
            #pragma unroll
            for (int q = 0; q < 4; q++) {
                unsigned short h = f2bf(v[q]);
                hv[q] = h;
                lv[q] = f2bf(v[q] - bf2f(h));
            }
            *(u16x4*)&Ahi[e * 72 + k0] = hv;
            *(u16x4*)&Alo[e * 72 + k0] = lv;
        }
        __syncthreads();

        // ---- layer 1: [64x64] @ [64x16 per wave], bf16x3
        facc4 acc1[4];
        #pragma unroll
        for (int mt = 0; mt < 4; mt++) {
            acc1[mt][0] = bias1; acc1[mt][1] = bias1;
            acc1[mt][2] = bias1; acc1[mt][3] = bias1;
        }
        #pragma unroll
        for (int ks = 0; ks < 2; ks++) {
            #pragma unroll
            for (int mt = 0; mt < 4; mt++) {
                const int ao = (mt * 16 + cl) * 72 + ks * 32 + lg * 8;
                bfrag8 ah = *(const bfrag8*)&Ahi[ao];
                bfrag8 al = *(const bfrag8*)&Alo[ao];
                acc1[mt] = __builtin_amdgcn_mfma_f32_16x16x32_bf16(ah, w1h[ks], acc1[mt], 0, 0, 0);
                acc1[mt] = __builtin_amdgcn_mfma_f32_16x16x32_bf16(al, w1h[ks], acc1[mt], 0, 0, 0);
                acc1[mt] = __builtin_amdgcn_mfma_f32_16x16x32_bf16(ah, w1l[ks], acc1[mt], 0, 0, 0);
            }
        }
        // relu + hi/lo split -> h1 planes (row = edge, col = h1 feature)
        #pragma unroll
        for (int mt = 0; mt < 4; mt++)
            #pragma unroll
            for (int j = 0; j < 4; j++) {
                float v = fmaxf(acc1[mt][j], 0.f);
                unsigned short h = f2bf(v);
                int m = mt * 16 + lg * 4 + j;           // D row mapping (m89)
                H1hi[m * 72 + wid * 16 + cl] = h;
                H1lo[m * 72 + wid * 16 + cl] = f2bf(v - bf2f(h));
            }
        __syncthreads();

        // ---- layer 2: [64x64] @ [64x32 per wave], bf16x3
        facc4 acc2[4][2];
        #pragma unroll
        for (int mt = 0; mt < 4; mt++)
            #pragma unroll
            for (int nt = 0; nt < 2; nt++) {
                acc2[mt][nt][0] = bias2[nt]; acc2[mt][nt][1] = bias2[nt];
                acc2[mt][nt][2] = bias2[nt]; acc2[mt][nt][3] = bias2[nt];
            }
        #pragma unroll
        for (int ks = 0; ks < 2; ks++) {
            #pragma unroll
            for (int mt = 0; mt < 4; mt++) {
                const int ao = (mt * 16 + cl) * 72 + ks * 32 + lg * 8;
                bfrag8 ah = *(const bfrag8*)&H1hi[ao];
                bfrag8 al = *(const bfrag8*)&H1lo[ao];
                #pragma unroll
                for (int nt = 0; nt < 2; nt++) {
                    acc2[mt][nt] = __builtin_amdgcn_mfma_f32_16x16x32_bf16(ah, w2h[nt][ks], acc2[mt][nt], 0, 0, 0);
                    acc2[mt][nt] = __builtin_amdgcn_mfma_f32_16x16x32_bf16(al, w2h[nt][ks], acc2[mt][nt], 0, 0, 0);
                    acc2[mt][nt] = __builtin_amdgcn_mfma_f32_16x16x32_bf16(ah, w2l[nt][ks], acc2[mt][nt], 0, 0, 0);
                }
            }
        }
        __syncthreads();   // all h1 reads done -> safe to overlay sRed

        // ---- spill relu(h2) to sRed[col][edge] (stride 65 words, 2-to-4-way max)
        #pragma unroll
        for (int mt = 0; mt < 4; mt++)
            #pragma unroll
            for (int nt = 0; nt < 2; nt++)
                #pragma unroll
                for (int j = 0; j < 4; j++) {
                    int e2 = mt * 16 + lg * 4 + j;
                    int c2 = wid * 32 + nt * 16 + cl;
                    sRed[c2 * 65 + e2] = fmaxf(acc2[mt][nt][j], 0.f);
                }
        __syncthreads();

        // ---- deterministic segment reduce: thread (c = t&127, q = t>>7) owns 8 nodes
        {
            const int c = t & 127, q = t >> 7;
            for (int n = q * 8; n < q * 8 + 8; n++) {
                int lo2 = sRP[n] - base - tb;     lo2 = lo2 < 0 ? 0 : lo2;
                int hi2 = sRP[n + 1] - base - tb; hi2 = hi2 > nv ? nv : hi2;
                float s = 0.f;
                for (int j = lo2; j < hi2; j++) s += sRed[c * 65 + j];
                if (hi2 > lo2) accs[n * 129 + c] += s;
            }
        }
        __syncthreads();
    }

    // write mean (exclusive ownership, non-atomic)
    for (int i = t; i < NBN * H2; i += 256) {
        int n = i >> 7, c = i & 127;
        int deg = sRP[n + 1] - sRP[n];
        float inv = (deg > 0) ? 1.f / (float)deg : 0.f;
        mean[(size_t)(n0 + n) * H2 + c] = accs[n * 129 + c] * inv;
    }
}

// ---------------- pass 5: node MLP, 4 nodes x 4 cols per thread
__global__ __launch_bounds__(256, 4) void node_kernel(
    const float* __restrict__ x,
    const float* __restrict__ W3, const float* __restrict__ b3,
    const float* __restrict__ W4, const float* __restrict__ b4,
    const float* __restrict__ mean,
    float* __restrict__ out)
{
    __shared__ float sIn[NBK * 133];
    __shared__ float sO1[NBK * 257];

    const int t  = threadIdx.x;
    const int n0 = blockIdx.x * NBK;
    const int s  = t & 63;          // col lane; cols s, s+64, s+128, s+192
    const int nw = (t >> 6) * 4;    // node base (wave-uniform)

    for (int i = t; i < NBK * 132; i += 256) {
        int n = i / 132, k = i - n * 132;
        sIn[n * 133 + k] = (k < XD) ? x[(n0 + n) * XD + k]
                                    : mean[(size_t)(n0 + n) * H2 + (k - XD)];
    }
    __syncthreads();

    // layer 3
    float acc[4][4];   // [node][col-instance]
    {
        float bb[4];
        #pragma unroll
        for (int ci = 0; ci < 4; ci++) bb[ci] = b3[s + 64 * ci];
        #pragma unroll
        for (int jn = 0; jn < 4; jn++)
            #pragma unroll
            for (int ci = 0; ci < 4; ci++) acc[jn][ci] = bb[ci];
    }
    #pragma unroll 4
    for (int k = 0; k < 132; k++) {
        float av[4];
        #pragma unroll
        for (int jn = 0; jn < 4; jn++) av[jn] = sIn[(nw + jn) * 133 + k];  // broadcast
        #pragma unroll
        for (int ci = 0; ci < 4; ci++) {
            float w = W3[k * H3 + s + 64 * ci];   // coalesced
            #pragma unroll
            for (int jn = 0; jn < 4; jn++)
                acc[jn][ci] = fmaf(av[jn], w, acc[jn][ci]);
        }
    }
    #pragma unroll
    for (int jn = 0; jn < 4; jn++)
        #pragma unroll
        for (int ci = 0; ci < 4; ci++)
            sO1[(nw + jn) * 257 + s + 64 * ci] = fmaxf(acc[jn][ci], 0.f);
    __syncthreads();

    // layer 4
    {
        float bb[4];
        #pragma unroll
        for (int ci = 0; ci < 4; ci++) bb[ci] = b4[s + 64 * ci];
        #pragma unroll
        for (int jn = 0; jn < 4; jn++)
            #pragma unroll
            for (int ci = 0; ci < 4; ci++) acc[jn][ci] = bb[ci];
    }
    #pragma unroll 4
    for (int k = 0; k < H3; k++) {
        float av[4];
        #pragma unroll
        for (int jn = 0; jn < 4; jn++) av[jn] = sO1[(nw + jn) * 257 + k];  // broadcast
        #pragma unroll
        for (int ci = 0; ci < 4; ci++) {
            float w = W4[k * H3 + s + 64 * ci];   // coalesced
            #pragma unroll
            for (int jn = 0; jn < 4; jn++)
                acc[jn][ci] = fmaf(av[jn], w, acc[jn][ci]);
        }
    }
    #pragma unroll
    for (int jn = 0; jn < 4; jn++)
        #pragma unroll
        for (int ci = 0; ci < 4; ci++)
            out[(size_t)(n0 + nw + jn) * H3 + s + 64 * ci] = fmaxf(acc[jn][ci], 0.f);
}

extern "C" void kernel_launch(void* const* d_in, const int* in_sizes, int n_in,
                              void* d_out, int out_size, void* d_ws, size_t ws_size,
                              hipStream_t stream) {
    const float* x    = (const float*)d_in[0];
    const int*   eidx = (const int*)  d_in[1];
    const float* ea   = (const float*)d_in[2];
    const float* W1   = (const float*)d_in[3];
    const float* b1   = (const float*)d_in[4];
    const float* W2   = (const float*)d_in[5];
    const float* b2   = (const float*)d_in[6];
    const float* W3   = (const float*)d_in[7];
    const float* b3   = (const float*)d_in[8];
    const float* W4   = (const float*)d_in[9];
    const float* b4   = (const float*)d_in[10];
    float* out = (float*)d_out;

    char* p = (char*)d_ws;
    float* mean    = (float*)p;  p += (size_t)NN * H2 * 4;
    int*   perm    = (int*)p;    p += (size_t)NE * 4;
    int*   row_ptr = (int*)p;    p += ((size_t)NN + 8) * 4;
    int*   cursor  = (int*)p;    p += (size_t)NN * 4;
    int*   cnt     = (int*)p;    p += (size_t)NN * 4;

    hipMemsetAsync(cnt, 0, (size_t)NN * 4, stream);

    hist_kernel <<<(NE + 255) / 256, 256, 0, stream>>>(eidx, cnt);
    scan_kernel <<<1, 1024, 0, stream>>>(cnt, row_ptr, cursor);
    build_kernel<<<(NE + 255) / 256, 256, 0, stream>>>(eidx, cursor, perm);
    edge_agg_kernel<<<NN / NBN, 256, 0, stream>>>(x, eidx, ea, W1, b1, W2, b2,
                                                  row_ptr, perm, mean);
    node_kernel<<<NN / NBK, 256, 0, stream>>>(x, W3, b3, W4, b4, mean, out);
}

// Round 2
// 1122.216 us; speedup vs baseline: 1.7004x; 1.1820x over previous
//
#include <hip/hip_runtime.h>
#include <hip/hip_bf16.h>

#define NN 100000
#define NE 1600000
#define XD 4
#define ED 39
#define K1 43    // XD+ED
#define H1 64
#define H2 128
#define H3 256
#define NBN 16   // nodes per block in edge_agg kernel
#define NBK2 32  // nodes per block in node kernel (100000 = 3125*32, no tail)

typedef short bfrag8 __attribute__((ext_vector_type(8)));
typedef float facc4  __attribute__((ext_vector_type(4)));
typedef unsigned short u16x4 __attribute__((ext_vector_type(4)));

static __device__ __forceinline__ unsigned short f2bf(float f) {
    union { float f; unsigned int u; } v; v.f = f;
    unsigned int r = v.u + 0x7fffu + ((v.u >> 16) & 1u);
    return (unsigned short)(r >> 16);
}
static __device__ __forceinline__ float bf2f(unsigned short h) {
    union { unsigned int u; float f; } v; v.u = ((unsigned int)h) << 16;
    return v.f;
}

// ---------------- pass 1: indegree histogram
__global__ __launch_bounds__(256) void hist_kernel(const int* __restrict__ eidx,
                                                   int* __restrict__ cnt) {
    int e = blockIdx.x * 256 + threadIdx.x;
    if (e < NE) atomicAdd(&cnt[eidx[e]], 1);
}

// ---------------- pass 2: single-block scan -> row_ptr (incl-shifted) + cursor (excl)
__global__ __launch_bounds__(1024) void scan_kernel(const int* __restrict__ cnt,
                                                    int* __restrict__ row_ptr,
                                                    int* __restrict__ cursor) {
    __shared__ int wsum[16];
    const int t = threadIdx.x, lane = t & 63, w = t >> 6;
    int carry = 0;
    if (t == 0) row_ptr[0] = 0;
    for (int base = 0; base < NN; base += 1024) {
        int i = base + t;
        int v = (i < NN) ? cnt[i] : 0;
        int s = v;
        #pragma unroll
        for (int d = 1; d < 64; d <<= 1) {
            int u = __shfl_up(s, d, 64);
            if (lane >= d) s += u;
        }
        if (lane == 63) wsum[w] = s;
        __syncthreads();
        if (w == 0 && lane < 16) {
            int e = wsum[lane];
            #pragma unroll
            for (int d = 1; d < 16; d <<= 1) {
                int u = __shfl_up(e, d, 64);
                if (lane >= d) e += u;
            }
            wsum[lane] = e;
        }
        __syncthreads();
        int woff = (w == 0) ? 0 : wsum[w - 1];
        int tot  = wsum[15];
        if (i < NN) {
            int incl = carry + woff + s;
            row_ptr[i + 1] = incl;
            cursor[i]      = incl - v;
        }
        carry += tot;
        __syncthreads();
    }
}

// ---------------- pass 3: scatter edge ids into dst-sorted order
__global__ __launch_bounds__(256) void build_kernel(const int* __restrict__ eidx,
                                                    int* __restrict__ cursor,
                                                    int* __restrict__ perm) {
    int e = blockIdx.x * 256 + threadIdx.x;
    if (e < NE) {
        int r = eidx[e];
        int pos = atomicAdd(&cursor[r], 1);
        perm[pos] = e;
    }
}

// ---------------- pass 3.5: split weights into transposed bf16 hi/lo planes
// W1T [64c][64k] (k pad 43->64), W2T [128][64], W3T [256][160] (132->160), W4T [256][256]
__global__ __launch_bounds__(256) void prep_kernel(
    const float* __restrict__ W1, const float* __restrict__ W2,
    const float* __restrict__ W3, const float* __restrict__ W4,
    unsigned short* __restrict__ W1h, unsigned short* __restrict__ W1l,
    unsigned short* __restrict__ W2h, unsigned short* __restrict__ W2l,
    unsigned short* __restrict__ W3h, unsigned short* __restrict__ W3l,
    unsigned short* __restrict__ W4h, unsigned short* __restrict__ W4l)
{
    int i = blockIdx.x * 256 + threadIdx.x;
    float w; unsigned short* ph; unsigned short* pl; int idx;
    if (i < 4096) {                                    // W1
        int c = i >> 6, k = i & 63;
        w = (k < K1) ? W1[k * H1 + c] : 0.f;
        ph = W1h; pl = W1l; idx = i;
    } else if (i < 4096 + 8192) {                      // W2
        int j = i - 4096; int c = j >> 6, k = j & 63;
        w = W2[k * H2 + c];
        ph = W2h; pl = W2l; idx = j;
    } else if (i < 4096 + 8192 + 40960) {              // W3
        int j = i - 12288; int c = j / 160, k = j - c * 160;
        w = (k < 132) ? W3[k * H3 + c] : 0.f;
        ph = W3h; pl = W3l; idx = j;
    } else if (i < 4096 + 8192 + 40960 + 65536) {      // W4
        int j = i - 53248; int c = j >> 8, k = j & 255;
        w = W4[k * H3 + c];
        ph = W4h; pl = W4l; idx = j;
    } else return;
    unsigned short h = f2bf(w);
    ph[idx] = h;
    pl[idx] = f2bf(w - bf2f(h));
}

// ---------------- pass 4: edge MLP via bf16x3 MFMA + deterministic aggregation
// T14 pipeline: next tile's perm/col/A-values prefetched into registers during
// current tile's MFMA + reduce phases; 5 barriers/tile.
__global__ __launch_bounds__(256, 3) void edge_agg_kernel(
    const float* __restrict__ x, const int* __restrict__ eidx,
    const float* __restrict__ ea,
    const unsigned short* __restrict__ W1h, const unsigned short* __restrict__ W1l,
    const float* __restrict__ b1,
    const unsigned short* __restrict__ W2h, const unsigned short* __restrict__ W2l,
    const float* __restrict__ b2,
    const int* __restrict__ row_ptr, const int* __restrict__ perm,
    float* __restrict__ mean)
{
    // union: Ahi|Alo|H1hi|H1lo each [64][72] bf16 (9216B) = 36864B; sRed [128][65] f32 overlays
    __shared__ __align__(16) unsigned short uMem[4 * 64 * 72];
    __shared__ float accs[16 * 129];
    __shared__ int sPerm[2][64], sCol[2][64], sRP[NBN + 1];

    unsigned short* Ahi  = uMem;
    unsigned short* Alo  = uMem + 64 * 72;
    unsigned short* H1hi = uMem + 2 * 64 * 72;
    unsigned short* H1lo = uMem + 3 * 64 * 72;
    float* sRed = (float*)uMem;

    const int t    = threadIdx.x;
    const int lane = t & 63;
    const int wid  = t >> 6;
    const int cl   = lane & 15;
    const int lg   = lane >> 4;
    const int n0   = blockIdx.x * NBN;

    // issue tile-0 perm/col loads first (overlap with weight-frag loads below)
    int p0 = -1, c0 = 0;
    if (t < 64) {
        int b0  = row_ptr[n0];
        int e0r = row_ptr[n0 + NBN];
        if (b0 + t < e0r) p0 = perm[b0 + t];
        if (p0 >= 0) c0 = eidx[NE + p0];
    }

    if (t <= NBN) sRP[t] = row_ptr[n0 + t];
    for (int i = t; i < NBN * H2; i += 256) accs[(i >> 7) * 129 + (i & 127)] = 0.f;

    // register-resident weight fragments from precomputed planes
    bfrag8 w1h_[2], w1l_[2], w2h_[2][2], w2l_[2][2];
    #pragma unroll
    for (int ks = 0; ks < 2; ks++) {
        const int off = (wid * 16 + cl) * 64 + ks * 32 + lg * 8;
        w1h_[ks] = *(const bfrag8*)&W1h[off];
        w1l_[ks] = *(const bfrag8*)&W1l[off];
    }
    #pragma unroll
    for (int nt = 0; nt < 2; nt++)
        #pragma unroll
        for (int ks = 0; ks < 2; ks++) {
            const int off = (wid * 32 + nt * 16 + cl) * 64 + ks * 32 + lg * 8;
            w2h_[nt][ks] = *(const bfrag8*)&W2h[off];
            w2l_[nt][ks] = *(const bfrag8*)&W2l[off];
        }
    const float bias1 = b1[wid * 16 + cl];
    const float bias2[2] = { b2[wid * 32 + cl], b2[wid * 32 + 16 + cl] };

    if (t < 64) { sPerm[0][t] = p0; sCol[0][t] = c0; }
    __syncthreads();

    const int base = sRP[0], cntE = sRP[NBN] - base;

    auto loadA = [&](float (&pv)[4][4], const int* sP, const int* sC) {
        #pragma unroll
        for (int r = 0; r < 4; r++) {
            const int e  = (t >> 4) + r * 16;
            const int k0 = (t & 15) * 4;
            const int ee = sP[e];
            if (ee >= 0) {
                if (k0 == 0) {
                    float4 xv = *(const float4*)&x[(size_t)sC[e] * XD];
                    pv[r][0] = xv.x; pv[r][1] = xv.y; pv[r][2] = xv.z; pv[r][3] = xv.w;
                } else {
                    const float* er = ea + (size_t)ee * ED;
                    #pragma unroll
                    for (int q = 0; q < 4; q++) {
                        int k = k0 + q;
                        pv[r][q] = (k < K1) ? er[k - XD] : 0.f;
                    }
                }
            } else {
                pv[r][0] = pv[r][1] = pv[r][2] = pv[r][3] = 0.f;
            }
        }
    };

    if (cntE > 0) {
        float pv[4][4];
        loadA(pv, sPerm[0], sCol[0]);
        int buf = 0;

        for (int tb = 0; tb < cntE; tb += 64) {
            const int nv   = min(64, cntE - tb);
            const int nbuf = buf ^ 1;

            // issue next tile's perm load
            int pp = -1;
            if (t < 64 && tb + 64 < cntE)
                pp = (tb + 64 + t < cntE) ? perm[base + tb + 64 + t] : -1;

            // write A regs -> LDS hi/lo planes (overlays sRed; prev reduce done)
            #pragma unroll
            for (int r = 0; r < 4; r++) {
                const int e  = (t >> 4) + r * 16;
                const int k0 = (t & 15) * 4;
                u16x4 hv, lv;
                #pragma unroll
                for (int q = 0; q < 4; q++) {
                    unsigned short h = f2bf(pv[r][q]);
                    hv[q] = h;
                    lv[q] = f2bf(pv[r][q] - bf2f(h));
                }
                *(u16x4*)&Ahi[e * 72 + k0] = hv;
                *(u16x4*)&Alo[e * 72 + k0] = lv;
            }
            __syncthreads();                                   // s1: A visible

            // next tile's col load (pp has had ~1 phase to land)
            int pc = 0;
            if (t < 64 && pp >= 0) pc = eidx[NE + pp];

            // ---- layer 1
            facc4 acc1[4];
            #pragma unroll
            for (int mt = 0; mt < 4; mt++) {
                acc1[mt][0] = bias1; acc1[mt][1] = bias1;
                acc1[mt][2] = bias1; acc1[mt][3] = bias1;
            }
            #pragma unroll
            for (int ks = 0; ks < 2; ks++) {
                #pragma unroll
                for (int mt = 0; mt < 4; mt++) {
                    const int ao = (mt * 16 + cl) * 72 + ks * 32 + lg * 8;
                    bfrag8 ah = *(const bfrag8*)&Ahi[ao];
                    bfrag8 al = *(const bfrag8*)&Alo[ao];
                    acc1[mt] = __builtin_amdgcn_mfma_f32_16x16x32_bf16(ah, w1h_[ks], acc1[mt], 0, 0, 0);
                    acc1[mt] = __builtin_amdgcn_mfma_f32_16x16x32_bf16(al, w1h_[ks], acc1[mt], 0, 0, 0);
                    acc1[mt] = __builtin_amdgcn_mfma_f32_16x16x32_bf16(ah, w1l_[ks], acc1[mt], 0, 0, 0);
                }
            }
            #pragma unroll
            for (int mt = 0; mt < 4; mt++)
                #pragma unroll
                for (int j = 0; j < 4; j++) {
                    float v = fmaxf(acc1[mt][j], 0.f);
                    unsigned short h = f2bf(v);
                    int m = mt * 16 + lg * 4 + j;
                    H1hi[m * 72 + wid * 16 + cl] = h;
                    H1lo[m * 72 + wid * 16 + cl] = f2bf(v - bf2f(h));
                }
            if (t < 64) { sPerm[nbuf][t] = pp; sCol[nbuf][t] = pc; }
            __syncthreads();                                   // s2: H1 + next perm visible

            // prefetch next tile's A values into regs (overlaps L2 + spill + reduce)
            if (tb + 64 < cntE) loadA(pv, sPerm[nbuf], sCol[nbuf]);

            // ---- layer 2
            facc4 acc2[4][2];
            #pragma unroll
            for (int mt = 0; mt < 4; mt++)
                #pragma unroll
                for (int nt = 0; nt < 2; nt++) {
                    acc2[mt][nt][0] = bias2[nt]; acc2[mt][nt][1] = bias2[nt];
                    acc2[mt][nt][2] = bias2[nt]; acc2[mt][nt][3] = bias2[nt];
                }
            #pragma unroll
            for (int ks = 0; ks < 2; ks++) {
                #pragma unroll
                for (int mt = 0; mt < 4; mt++) {
                    const int ao = (mt * 16 + cl) * 72 + ks * 32 + lg * 8;
                    bfrag8 ah = *(const bfrag8*)&H1hi[ao];
                    bfrag8 al = *(const bfrag8*)&H1lo[ao];
                    #pragma unroll
                    for (int nt = 0; nt < 2; nt++) {
                        acc2[mt][nt] = __builtin_amdgcn_mfma_f32_16x16x32_bf16(ah, w2h_[nt][ks], acc2[mt][nt], 0, 0, 0);
                        acc2[mt][nt] = __builtin_amdgcn_mfma_f32_16x16x32_bf16(al, w2h_[nt][ks], acc2[mt][nt], 0, 0, 0);
                        acc2[mt][nt] = __builtin_amdgcn_mfma_f32_16x16x32_bf16(ah, w2l_[nt][ks], acc2[mt][nt], 0, 0, 0);
                    }
                }
            }
            __syncthreads();                                   // s3: h1 reads done -> sRed safe

            #pragma unroll
            for (int mt = 0; mt < 4; mt++)
                #pragma unroll
                for (int nt = 0; nt < 2; nt++)
                    #pragma unroll
                    for (int j = 0; j < 4; j++) {
                        int e2 = mt * 16 + lg * 4 + j;
                        int c2 = wid * 32 + nt * 16 + cl;
                        sRed[c2 * 65 + e2] = fmaxf(acc2[mt][nt][j], 0.f);
                    }
            __syncthreads();                                   // s4: sRed complete

            {
                const int c = t & 127, q = t >> 7;
                for (int n = q * 8; n < q * 8 + 8; n++) {
                    int lo2 = sRP[n] - base - tb;     lo2 = lo2 < 0 ? 0 : lo2;
                    int hi2 = sRP[n + 1] - base - tb; hi2 = hi2 > nv ? nv : hi2;
                    float s = 0.f;
                    for (int j = lo2; j < hi2; j++) s += sRed[c * 65 + j];
                    if (hi2 > lo2) accs[n * 129 + c] += s;
                }
            }
            __syncthreads();                                   // s5: reduce done
            buf = nbuf;
        }
    }

    for (int i = t; i < NBN * H2; i += 256) {
        int n = i >> 7, c = i & 127;
        int deg = sRP[n + 1] - sRP[n];
        float inv = (deg > 0) ? 1.f / (float)deg : 0.f;
        mean[(size_t)(n0 + n) * H2 + c] = accs[n * 129 + c] * inv;
    }
}

// ---------------- pass 5: node MLP via bf16x3 MFMA, 32 nodes/block
// LDS union: A [32][168] hi/lo bf16 (21504B) | H [32][264] hi/lo (33792B)
__global__ __launch_bounds__(256, 4) void node_kernel(
    const float* __restrict__ x,
    const float* __restrict__ mean,
    const unsigned short* __restrict__ W3h, const unsigned short* __restrict__ W3l,
    const float* __restrict__ b3,
    const unsigned short* __restrict__ W4h, const unsigned short* __restrict__ W4l,
    const float* __restrict__ b4,
    float* __restrict__ out)
{
    __shared__ __align__(16) unsigned short uM[2 * 32 * 264];   // 33792 B
    unsigned short* Ah = uM;                  // [32][168]
    unsigned short* Al = uM + 32 * 168;
    unsigned short* Hh = uM;                  // [32][264]
    unsigned short* Hl = uM + 32 * 264;

    const int t    = threadIdx.x;
    const int lane = t & 63;
    const int w    = t >> 6;
    const int cl   = lane & 15;
    const int lg   = lane >> 4;
    const int n0   = blockIdx.x * NBK2;

    // stage A: k = [x(4) | mean(128) | 0-pad to 160], hi/lo split
    {
        const int n   = t & 31;
        const int kq0 = t >> 5;    // 0..7
        #pragma unroll
        for (int it = 0; it < 5; it++) {
            const int k0 = (kq0 + it * 8) * 4;   // 0..156
            float v[4];
            if (k0 == 0) {
                float4 xv = *(const float4*)&x[(size_t)(n0 + n) * XD];
                v[0] = xv.x; v[1] = xv.y; v[2] = xv.z; v[3] = xv.w;
            } else if (k0 <= 128) {
                float4 mv = *(const float4*)&mean[(size_t)(n0 + n) * H2 + (k0 - XD)];
                v[0] = mv.x; v[1] = mv.y; v[2] = mv.z; v[3] = mv.w;
            } else {
                v[0] = v[1] = v[2] = v[3] = 0.f;
            }
            u16x4 hv, lv;
            #pragma unroll
            for (int q = 0; q < 4; q++) {
                unsigned short h = f2bf(v[q]);
                hv[q] = h;
                lv[q] = f2bf(v[q] - bf2f(h));
            }
            *(u16x4*)&Ah[n * 168 + k0] = hv;
            *(u16x4*)&Al[n * 168 + k0] = lv;
        }
    }
    __syncthreads();

    // ---- GEMM1: [32 x 160] @ [160 x 256]; wave w owns cols [w*64, w*64+64)
    facc4 acc[2][4];
    #pragma unroll
    for (int nt = 0; nt < 4; nt++) {
        float b = b3[w * 64 + nt * 16 + cl];
        #pragma unroll
        for (int mt = 0; mt < 2; mt++) {
            acc[mt][nt][0] = b; acc[mt][nt][1] = b;
            acc[mt][nt][2] = b; acc[mt][nt][3] = b;
        }
    }
    #pragma unroll
    for (int ks = 0; ks < 5; ks++) {
        bfrag8 ah[2], al[2];
        #pragma unroll
        for (int mt = 0; mt < 2; mt++) {
            const int ao = (mt * 16 + cl) * 168 + ks * 32 + lg * 8;
            ah[mt] = *(const bfrag8*)&Ah[ao];
            al[mt] = *(const bfrag8*)&Al[ao];
        }
        #pragma unroll
        for (int nt = 0; nt < 4; nt++) {
            const size_t wo = (size_t)(w * 64 + nt * 16 + cl) * 160 + ks * 32 + lg * 8;
            bfrag8 bh = *(const bfrag8*)&W3h[wo];
            bfrag8 bl = *(const bfrag8*)&W3l[wo];
            #pragma unroll
            for (int mt = 0; mt < 2; mt++) {
                acc[mt][nt] = __builtin_amdgcn_mfma_f32_16x16x32_bf16(ah[mt], bh, acc[mt][nt], 0, 0, 0);
                acc[mt][nt] = __builtin_amdgcn_mfma_f32_16x16x32_bf16(al[mt], bh, acc[mt][nt], 0, 0, 0);
                acc[mt][nt] = __builtin_amdgcn_mfma_f32_16x16x32_bf16(ah[mt], bl, acc[mt][nt], 0, 0, 0);
            }
        }
    }
    __syncthreads();   // A reads done -> H may overlay

    #pragma unroll
    for (int mt = 0; mt < 2; mt++)
        #pragma unroll
        for (int nt = 0; nt < 4; nt++)
            #pragma unroll
            for (int j = 0; j < 4; j++) {
                float v = fmaxf(acc[mt][nt][j], 0.f);
                const int r = mt * 16 + lg * 4 + j;
                const int c = w * 64 + nt * 16 + cl;
                unsigned short h = f2bf(v);
                Hh[r * 264 + c] = h;
                Hl[r * 264 + c] = f2bf(v - bf2f(h));
            }
    __syncthreads();   // H visible

    // ---- GEMM2: [32 x 256] @ [256 x 256]
    facc4 acc2[2][4];
    #pragma unroll
    for (int nt = 0; nt < 4; nt++) {
        float b = b4[w * 64 + nt * 16 + cl];
        #pragma unroll
        for (int mt = 0; mt < 2; mt++) {
            acc2[mt][nt][0] = b; acc2[mt][nt][1] = b;
            acc2[mt][nt][2] = b; acc2[mt][nt][3] = b;
        }
    }
    #pragma unroll
    for (int ks = 0; ks < 8; ks++) {
        bfrag8 ah[2], al[2];
        #pragma unroll
        for (int mt = 0; mt < 2; mt++) {
            const int ao = (mt * 16 + cl) * 264 + ks * 32 + lg * 8;
            ah[mt] = *(const bfrag8*)&Hh[ao];
            al[mt] = *(const bfrag8*)&Hl[ao];
        }
        #pragma unroll
        for (int nt = 0; nt < 4; nt++) {
            const size_t wo = (size_t)(w * 64 + nt * 16 + cl) * 256 + ks * 32 + lg * 8;
            bfrag8 bh = *(const bfrag8*)&W4h[wo];
            bfrag8 bl = *(const bfrag8*)&W4l[wo];
            #pragma unroll
            for (int mt = 0; mt < 2; mt++) {
                acc2[mt][nt] = __builtin_amdgcn_mfma_f32_16x16x32_bf16(ah[mt], bh, acc2[mt][nt], 0, 0, 0);
                acc2[mt][nt] = __builtin_amdgcn_mfma_f32_16x16x32_bf16(al[mt], bh, acc2[mt][nt], 0, 0, 0);
                acc2[mt][nt] = __builtin_amdgcn_mfma_f32_16x16x32_bf16(ah[mt], bl, acc2[mt][nt], 0, 0, 0);
            }
        }
    }
    #pragma unroll
    for (int mt = 0; mt < 2; mt++)
        #pragma unroll
        for (int nt = 0; nt < 4; nt++)
            #pragma unroll
            for (int j = 0; j < 4; j++)
                out[(size_t)(n0 + mt * 16 + lg * 4 + j) * H3 + w * 64 + nt * 16 + cl] =
                    fmaxf(acc2[mt][nt][j], 0.f);
}

extern "C" void kernel_launch(void* const* d_in, const int* in_sizes, int n_in,
                              void* d_out, int out_size, void* d_ws, size_t ws_size,
                              hipStream_t stream) {
    const float* x    = (const float*)d_in[0];
    const int*   eidx = (const int*)  d_in[1];
    const float* ea   = (const float*)d_in[2];
    const float* W1   = (const float*)d_in[3];
    const float* b1   = (const float*)d_in[4];
    const float* W2   = (const float*)d_in[5];
    const float* b2   = (const float*)d_in[6];
    const float* W3   = (const float*)d_in[7];
    const float* b3   = (const float*)d_in[8];
    const float* W4   = (const float*)d_in[9];
    const float* b4   = (const float*)d_in[10];
    float* out = (float*)d_out;

    char* p = (char*)d_ws;
    float* mean    = (float*)p;  p += (size_t)NN * H2 * 4;
    int*   perm    = (int*)p;    p += (size_t)NE * 4;
    int*   row_ptr = (int*)p;    p += ((size_t)NN + 8) * 4;
    int*   cursor  = (int*)p;    p += (size_t)NN * 4;
    int*   cnt     = (int*)p;    p += (size_t)NN * 4;

    // weight bf16 hi/lo planes overlay cursor+cnt (800000 B, dead after build_kernel;
    // prep runs after build, planes consumed by edge/node; rebuilt every replay)
    unsigned short* wp = (unsigned short*)cursor;
    unsigned short* W1h_ = wp; wp += 64 * 64;
    unsigned short* W1l_ = wp; wp += 64 * 64;
    unsigned short* W2h_ = wp; wp += 128 * 64;
    unsigned short* W2l_ = wp; wp += 128 * 64;
    unsigned short* W3h_ = wp; wp += 256 * 160;
    unsigned short* W3l_ = wp; wp += 256 * 160;
    unsigned short* W4h_ = wp; wp += 256 * 256;
    unsigned short* W4l_ = wp; wp += 256 * 256;   // total 475136 B < 800000 B

    hipMemsetAsync(cnt, 0, (size_t)NN * 4, stream);

    hist_kernel <<<(NE + 255) / 256, 256, 0, stream>>>(eidx, cnt);
    scan_kernel <<<1, 1024, 0, stream>>>(cnt, row_ptr, cursor);
    build_kernel<<<(NE + 255) / 256, 256, 0, stream>>>(eidx, cursor, perm);
    prep_kernel <<<(4096 + 8192 + 40960 + 65536 + 255) / 256, 256, 0, stream>>>(
        W1, W2, W3, W4, W1h_, W1l_, W2h_, W2l_, W3h_, W3l_, W4h_, W4l_);
    edge_agg_kernel<<<NN / NBN, 256, 0, stream>>>(x, eidx, ea, W1h_, W1l_, b1,
                                                  W2h_, W2l_, b2, row_ptr, perm, mean);
    node_kernel<<<NN / NBK2, 256, 0, stream>>>(x, mean, W3h_, W3l_, b3,
                                               W4h_, W4l_, b4, out);
}